// Round 2
// baseline (24159.904 us; speedup 1.0000x reference)
//
#include <hip/hip_runtime.h>
#include <hip/hip_fp16.h>

#define BB 8
#define SS 4096
#define II 512
#define HH 512

typedef _Float16 f16x8 __attribute__((ext_vector_type(8)));
typedef float f32x4 __attribute__((ext_vector_type(4)));

__device__ __forceinline__ float tanh_fast(float x) {
    float ax = fabsf(x);
    float t  = exp2f(-2.8853900817779268f * ax);   // e^{-2|x|}
    float r  = (1.0f - t) * __builtin_amdgcn_rcpf(1.0f + t);
    return copysignf(r, x);
}

// ---------------------------------------------------------------------------
// Phase 1: xp[m][n] = sum_k x[m][k] * W_ih[n][k] + b_ih[n]   (M=32768,N=512,K=512)
// ---------------------------------------------------------------------------
#define P1_TM 64
#define P1_TN 64
#define P1_TK 16
#define P1_LDP 68

__global__ __launch_bounds__(256) void xp_gemm(const float* __restrict__ x,
                                               const float* __restrict__ wih,
                                               const float* __restrict__ bih,
                                               float* __restrict__ out) {
    __shared__ float As[P1_TK][P1_LDP];
    __shared__ float Bs[P1_TK][P1_LDP];
    const int tid = threadIdx.x;
    const int n0  = blockIdx.x * P1_TN;
    const int m0  = blockIdx.y * P1_TM;
    const int row = tid >> 2;
    const int f4  = tid & 3;
    const int ty  = tid >> 4;
    const int tx  = tid & 15;

    float acc[4][4];
#pragma unroll
    for (int r = 0; r < 4; ++r)
#pragma unroll
        for (int c = 0; c < 4; ++c) acc[r][c] = 0.0f;

    const float* xa = x   + (size_t)(m0 + row) * II + f4 * 4;
    const float* wb = wih + (size_t)(n0 + row) * II + f4 * 4;

    for (int kb = 0; kb < II; kb += P1_TK) {
        float4 av = *(const float4*)(xa + kb);
        float4 bv = *(const float4*)(wb + kb);
        __syncthreads();
        As[f4 * 4 + 0][row] = av.x; As[f4 * 4 + 1][row] = av.y;
        As[f4 * 4 + 2][row] = av.z; As[f4 * 4 + 3][row] = av.w;
        Bs[f4 * 4 + 0][row] = bv.x; Bs[f4 * 4 + 1][row] = bv.y;
        Bs[f4 * 4 + 2][row] = bv.z; Bs[f4 * 4 + 3][row] = bv.w;
        __syncthreads();
#pragma unroll
        for (int kk = 0; kk < P1_TK; ++kk) {
            const float* a4 = &As[kk][ty * 4];
            const float* b4 = &Bs[kk][tx * 4];
#pragma unroll
            for (int r = 0; r < 4; ++r)
#pragma unroll
                for (int c = 0; c < 4; ++c)
                    acc[r][c] = fmaf(a4[r], b4[c], acc[r][c]);
        }
    }

    const float4 bias = *(const float4*)&bih[n0 + tx * 4];
#pragma unroll
    for (int r = 0; r < 4; ++r) {
        float4 v;
        v.x = acc[r][0] + bias.x;
        v.y = acc[r][1] + bias.y;
        v.z = acc[r][2] + bias.z;
        v.w = acc[r][3] + bias.w;
        *(float4*)(out + (size_t)(m0 + ty * 4 + r) * HH + n0 + tx * 4) = v;
    }
}

// ---------------------------------------------------------------------------
// Phase 2: MFMA recurrence. 2 worker blocks (at blockIdx 0 and 8 so the usual
// round-robin XCD mapping co-locates them), 256 threads (4 waves) each.
// Block p owns output rows n in [256p, 256p+256): W_hh rows as fp16 B-frags
// in registers (64 frags x 4 VGPR = 256 VGPR/lane at 1 wave/SIMD budget 512).
// All 8 batches ride the M dim of mfma_f32_16x16x32_f16 (rows 8..15 unused).
// Per step: poll other's flag -> load h fragments (pre-swizzled in mailbox)
// -> 64 MFMA -> tanh -> store h to d_out + swizzle own half into mailbox ->
// release fence -> flag. 2-deep ping-pong mailbox; agent-scope fences handle
// cross-XCD L2 non-coherence.
// ---------------------------------------------------------------------------
__global__ __launch_bounds__(256, 1) void rnn_scan2(
    const float* __restrict__ whh, const float* __restrict__ bhh,
    float* __restrict__ io, unsigned int* __restrict__ flags,
    uint4* __restrict__ mail /* [2][16][64] uint4 */) {
    const int bid = blockIdx.x;
    if (bid != 0 && bid != 8) return;
    const int p   = bid ? 1 : 0;
    const int tid = threadIdx.x;
    const int w   = tid >> 6;        // wave 0..3
    const int l   = tid & 63;        // lane
    const int l15 = l & 15;
    const int lh  = l >> 4;          // 0..3

    __shared__ _Float16 hh[8][264];  // own-half h, padded pitch (264*2B)

    // n columns owned by this lane (one per nb_local i)
    int ncol[4];
#pragma unroll
    for (int i = 0; i < 4; ++i) ncol[i] = p * 256 + (w * 4 + i) * 16 + l15;

    // --- B fragments: B[k][n] = W_hh[n][k]; lane holds col l&15, k=(l>>4)*8+e
    f16x8 wf[4][16];
#pragma unroll
    for (int i = 0; i < 4; ++i) {
        const float* wr = whh + (size_t)ncol[i] * HH;
#pragma unroll
        for (int kb = 0; kb < 16; ++kb) {
            const int k0 = kb * 32 + lh * 8;
            float4 x0 = *(const float4*)(wr + k0);
            float4 x1 = *(const float4*)(wr + k0 + 4);
            f16x8 f;
            f[0] = (_Float16)x0.x; f[1] = (_Float16)x0.y;
            f[2] = (_Float16)x0.z; f[3] = (_Float16)x0.w;
            f[4] = (_Float16)x1.x; f[5] = (_Float16)x1.y;
            f[6] = (_Float16)x1.z; f[7] = (_Float16)x1.w;
            wf[i][kb] = f;
        }
    }
    float bv[4];
#pragma unroll
    for (int i = 0; i < 4; ++i) bv[i] = bhh[ncol[i]];

    for (int t = 0; t < SS; ++t) {
        // xp prefetch for this step (valid output lanes: lh<2 hold m=0..7)
        float xq[4][4];
        if (lh < 2) {
#pragma unroll
            for (int r = 0; r < 4; ++r) {
                const int m = lh * 4 + r;
                const float* row = io + ((size_t)m * SS + t) * HH;
#pragma unroll
                for (int i = 0; i < 4; ++i) xq[r][i] = row[ncol[i]];
            }
        }

        f32x4 acc[4];
#pragma unroll
        for (int i = 0; i < 4; ++i) acc[i] = (f32x4){0.f, 0.f, 0.f, 0.f};

        if (t > 0) {
            if (tid == 0) {
                while (__hip_atomic_load(flags + (1 - p) * 64, __ATOMIC_RELAXED,
                                         __HIP_MEMORY_SCOPE_AGENT) < (unsigned)t)
                    __builtin_amdgcn_s_sleep(1);
            }
            __syncthreads();
            __threadfence();   // acquire: invalidate stale L2 before mailbox reads

            const uint4* mb = mail + (size_t)((t - 1) & 1) * 1024;
            f16x8 af[16];
#pragma unroll
            for (int kb = 0; kb < 16; ++kb) {
                uint4 u = mb[kb * 64 + l];
                af[kb] = __builtin_bit_cast(f16x8, u);
            }
#pragma unroll
            for (int kb = 0; kb < 16; ++kb)
#pragma unroll
                for (int i = 0; i < 4; ++i)
                    acc[i] = __builtin_amdgcn_mfma_f32_16x16x32_f16(
                        af[kb], wf[i][kb], acc[i], 0, 0, 0);
        }

        // readout: D col = lane&15, row m = (lane>>4)*4 + reg (m<8 valid)
        if (lh < 2) {
#pragma unroll
            for (int r = 0; r < 4; ++r) {
                const int m = lh * 4 + r;
                float* row = io + ((size_t)m * SS + t) * HH;
#pragma unroll
                for (int i = 0; i < 4; ++i) {
                    float v = tanh_fast(acc[i][r] + xq[r][i] + bv[i]);
                    row[ncol[i]] = v;
                    hh[m][(w * 4 + i) * 16 + l15] = (_Float16)v;
                }
            }
        }
        __syncthreads();

        // swizzle own half into A-fragment order: entry(kb_local, ll) holds
        // h[m=ll&15][k = (8p+kb_local)*32 + (ll>>4)*8 + e], zeros for m>=8
#pragma unroll
        for (int e2 = 0; e2 < 2; ++e2) {
            const int e   = tid * 2 + e2;
            const int kbl = e >> 6;
            const int ll  = e & 63;
            const int m   = ll & 15;
            uint4 v = make_uint4(0u, 0u, 0u, 0u);
            if (m < 8) {
                const int nloc = kbl * 32 + (ll >> 4) * 8;
                v = *(const uint4*)&hh[m][nloc];
            }
            mail[(size_t)(t & 1) * 1024 + (size_t)(p * 8 + kbl) * 64 + ll] = v;
        }
        __threadfence();   // release: drain + write back L2 before flag
        __syncthreads();   // all threads' stores fenced
        if (tid == 0)
            __hip_atomic_store(flags + p * 64, (unsigned)(t + 1),
                               __ATOMIC_RELAXED, __HIP_MEMORY_SCOPE_AGENT);
    }
}

// ---------------------------------------------------------------------------
extern "C" void kernel_launch(void* const* d_in, const int* in_sizes, int n_in,
                              void* d_out, int out_size, void* d_ws, size_t ws_size,
                              hipStream_t stream) {
    const float* x   = (const float*)d_in[0];
    const float* wih = (const float*)d_in[1];
    const float* whh = (const float*)d_in[2];
    const float* bih = (const float*)d_in[3];
    const float* bhh = (const float*)d_in[4];
    float* out = (float*)d_out;

    unsigned int* flags = (unsigned int*)d_ws;                  // 2 flags, 256B apart
    uint4* mail = (uint4*)((char*)d_ws + 4096);                 // 2*16*64*16B = 32KB

    hipMemsetAsync(d_ws, 0, 4096, stream);                      // reset flags each call

    dim3 g1(HH / P1_TN, (BB * SS) / P1_TM);
    xp_gemm<<<g1, 256, 0, stream>>>(x, wih, bih, out);

    rnn_scan2<<<dim3(16), dim3(256), 0, stream>>>(whh, bhh, out, flags, mail);
}

// Round 3
// 15469.313 us; speedup vs baseline: 1.5618x; 1.5618x over previous
//
#include <hip/hip_runtime.h>
#include <hip/hip_fp16.h>

#define BB 8
#define SS 4096
#define II 512
#define HH 512

typedef _Float16 f16x8 __attribute__((ext_vector_type(8)));
typedef float f32x4 __attribute__((ext_vector_type(4)));

__device__ __forceinline__ float tanh_fast(float x) {
    float ax = fabsf(x);
    float t  = __builtin_amdgcn_exp2f(-2.8853900817779268f * ax);   // e^{-2|x|}
    float r  = (1.0f - t) * __builtin_amdgcn_rcpf(1.0f + t);
    return copysignf(r, x);
}

// ---------------------------------------------------------------------------
// Phase 1: xp[m][n] = sum_k x[m][k] * W_ih[n][k] + b_ih[n]   (M=32768,N=512,K=512)
// ---------------------------------------------------------------------------
#define P1_TM 64
#define P1_TN 64
#define P1_TK 16
#define P1_LDP 68

__global__ __launch_bounds__(256) void xp_gemm(const float* __restrict__ x,
                                               const float* __restrict__ wih,
                                               const float* __restrict__ bih,
                                               float* __restrict__ out) {
    __shared__ float As[P1_TK][P1_LDP];
    __shared__ float Bs[P1_TK][P1_LDP];
    const int tid = threadIdx.x;
    const int n0  = blockIdx.x * P1_TN;
    const int m0  = blockIdx.y * P1_TM;
    const int row = tid >> 2;
    const int f4  = tid & 3;
    const int ty  = tid >> 4;
    const int tx  = tid & 15;

    float acc[4][4];
#pragma unroll
    for (int r = 0; r < 4; ++r)
#pragma unroll
        for (int c = 0; c < 4; ++c) acc[r][c] = 0.0f;

    const float* xa = x   + (size_t)(m0 + row) * II + f4 * 4;
    const float* wb = wih + (size_t)(n0 + row) * II + f4 * 4;

    for (int kb = 0; kb < II; kb += P1_TK) {
        float4 av = *(const float4*)(xa + kb);
        float4 bv = *(const float4*)(wb + kb);
        __syncthreads();
        As[f4 * 4 + 0][row] = av.x; As[f4 * 4 + 1][row] = av.y;
        As[f4 * 4 + 2][row] = av.z; As[f4 * 4 + 3][row] = av.w;
        Bs[f4 * 4 + 0][row] = bv.x; Bs[f4 * 4 + 1][row] = bv.y;
        Bs[f4 * 4 + 2][row] = bv.z; Bs[f4 * 4 + 3][row] = bv.w;
        __syncthreads();
#pragma unroll
        for (int kk = 0; kk < P1_TK; ++kk) {
            const float* a4 = &As[kk][ty * 4];
            const float* b4 = &Bs[kk][tx * 4];
#pragma unroll
            for (int r = 0; r < 4; ++r)
#pragma unroll
                for (int c = 0; c < 4; ++c)
                    acc[r][c] = fmaf(a4[r], b4[c], acc[r][c]);
        }
    }

    const float4 bias = *(const float4*)&bih[n0 + tx * 4];
#pragma unroll
    for (int r = 0; r < 4; ++r) {
        float4 v;
        v.x = acc[r][0] + bias.x;
        v.y = acc[r][1] + bias.y;
        v.z = acc[r][2] + bias.z;
        v.w = acc[r][3] + bias.w;
        *(float4*)(out + (size_t)(m0 + ty * 4 + r) * HH + n0 + tx * 4) = v;
    }
}

// ---------------------------------------------------------------------------
// Phase 2: single workgroup (256 threads, 4 waves, 1 CU), all 8 batches in the
// M dim of mfma_f32_16x16x32_f16. Wave w owns n-cols [128w,128w+128) = tiles
// gi 0..7; tiles 0..5 have W fp16 B-frags in registers (384 regs/lane, unified
// VGPR+AGPR file), tiles 6..7 stream from LDS (128 KB). h exchanged via an
// 8 KB double-buffered LDS A-frag buffer, 1 barrier/step. A rows 8..15 read
// the same LDS bytes as rows 0..7 -> D rows 8..15 duplicate rows 0..7, so all
// 64 lanes hold valid outputs (no shuffles). No fences, no atomics, no d_ws.
// ---------------------------------------------------------------------------
#define WLDS_B  (4 * 2 * 16 * 1024)     // 131072 B: W frags (4 waves x 2 tiles)
#define ABUF_B  (2 * 16 * 512)          // 16384 B: double-buffered A frags
#define LDS_TOT (WLDS_B + ABUF_B)       // 147456 <= 163840

__global__ __launch_bounds__(256, 1) void rnn_scan3(const float* __restrict__ whh,
                                                    const float* __restrict__ bhh,
                                                    float* __restrict__ io) {
    extern __shared__ char lds[];
    const int tid = threadIdx.x;
    const int w   = tid >> 6;       // wave 0..3
    const int l   = tid & 63;
    const int l15 = l & 15;
    const int lq  = l >> 4;         // 0..3

    // ---- W register fragments: tiles gi 0..5 of this wave.
    // B-frag (verified r2): lane holds col n = base+l15, k = kb*32 + lq*8 + e.
    f16x8 wf[6][16];
#pragma unroll
    for (int gi = 0; gi < 6; ++gi) {
        const float* wr = whh + (size_t)(w * 128 + gi * 16 + l15) * HH;
#pragma unroll
        for (int kb = 0; kb < 16; ++kb) {
            const int k0 = kb * 32 + lq * 8;
            float4 f0 = *(const float4*)(wr + k0);
            float4 f1 = *(const float4*)(wr + k0 + 4);
            f16x8 f;
            f[0] = (_Float16)f0.x; f[1] = (_Float16)f0.y;
            f[2] = (_Float16)f0.z; f[3] = (_Float16)f0.w;
            f[4] = (_Float16)f1.x; f[5] = (_Float16)f1.y;
            f[6] = (_Float16)f1.z; f[7] = (_Float16)f1.w;
            wf[gi][kb] = f;
        }
    }
    // ---- W LDS fragments: tiles gi 6,7 (wave-private region, linear layout)
    const unsigned wbase = w * 32768u + l * 16u;
#pragma unroll
    for (int tt = 0; tt < 2; ++tt) {
        const float* wr = whh + (size_t)(w * 128 + (6 + tt) * 16 + l15) * HH;
#pragma unroll
        for (int kb = 0; kb < 16; ++kb) {
            const int k0 = kb * 32 + lq * 8;
            float4 f0 = *(const float4*)(wr + k0);
            float4 f1 = *(const float4*)(wr + k0 + 4);
            f16x8 f;
            f[0] = (_Float16)f0.x; f[1] = (_Float16)f0.y;
            f[2] = (_Float16)f0.z; f[3] = (_Float16)f0.w;
            f[4] = (_Float16)f1.x; f[5] = (_Float16)f1.y;
            f[6] = (_Float16)f1.z; f[7] = (_Float16)f1.w;
            *(f16x8*)(lds + wbase + tt * 16384u + kb * 1024u) = f;
        }
    }

    // ---- per-lane output assignment: q=lq; tiles gi = (q>>1)*4 + i (i 0..3),
    // m = (q&1)*4 + r (valid for all lanes via the A-row duplication trick).
    float bq[4];
    int   noff[4];   // n-index per i
    int   sad[4];    // static scatter addr into A-buf per i (+ r*16)
#pragma unroll
    for (int i = 0; i < 4; ++i) {
        const int gi = (lq >> 1) * 4 + i;
        const int n  = w * 128 + gi * 16 + l15;
        noff[i] = n;
        bq[i]   = bhh[n];
        sad[i]  = (n >> 5) * 512 + ((n >> 3) & 3) * 128 + (lq & 1) * 64 + (n & 7) * 2;
    }
    int off[4][4];   // global byte offsets: m*SS*HH*4 + n*4
#pragma unroll
    for (int i = 0; i < 4; ++i)
#pragma unroll
        for (int r = 0; r < 4; ++r)
            off[i][r] = ((lq & 1) * 4 + r) * (SS * HH * 4) + noff[i] * 4;

    // xp for t=0
    float xq[4][4];
#pragma unroll
    for (int i = 0; i < 4; ++i)
#pragma unroll
        for (int r = 0; r < 4; ++r)
            xq[i][r] = *(const float*)((const char*)io + off[i][r]);

    const unsigned ardoff = (unsigned)((lq * 8 + (l15 & 7)) * 16);
    char* pbs = (char*)io;                 // advances by 2048 B (= HH floats) per t

#pragma unroll 1
    for (int t = 0; t < SS; ++t) {
        f32x4 acc[8];
#pragma unroll
        for (int i = 0; i < 8; ++i) acc[i] = (f32x4){0.f, 0.f, 0.f, 0.f};

        if (t > 0) {
            const unsigned abase = WLDS_B + (unsigned)((t & 1) * 8192) + ardoff;
#pragma unroll
            for (int kb = 0; kb < 16; ++kb) {
                f16x8 af = *(const f16x8*)(lds + abase + kb * 512u);
                f16x8 w6 = *(const f16x8*)(lds + wbase + kb * 1024u);
                f16x8 w7 = *(const f16x8*)(lds + wbase + 16384u + kb * 1024u);
                acc[0] = __builtin_amdgcn_mfma_f32_16x16x32_f16(af, wf[0][kb], acc[0], 0, 0, 0);
                acc[1] = __builtin_amdgcn_mfma_f32_16x16x32_f16(af, wf[1][kb], acc[1], 0, 0, 0);
                acc[2] = __builtin_amdgcn_mfma_f32_16x16x32_f16(af, wf[2][kb], acc[2], 0, 0, 0);
                acc[3] = __builtin_amdgcn_mfma_f32_16x16x32_f16(af, wf[3][kb], acc[3], 0, 0, 0);
                acc[4] = __builtin_amdgcn_mfma_f32_16x16x32_f16(af, wf[4][kb], acc[4], 0, 0, 0);
                acc[5] = __builtin_amdgcn_mfma_f32_16x16x32_f16(af, wf[5][kb], acc[5], 0, 0, 0);
                acc[6] = __builtin_amdgcn_mfma_f32_16x16x32_f16(af, w6, acc[6], 0, 0, 0);
                acc[7] = __builtin_amdgcn_mfma_f32_16x16x32_f16(af, w7, acc[7], 0, 0, 0);
            }
        }

        // prefetch next step's xp (consumed after the barrier, next iteration)
        float xn[4][4] = {};
        if (t + 1 < SS) {
#pragma unroll
            for (int i = 0; i < 4; ++i)
#pragma unroll
                for (int r = 0; r < 4; ++r)
                    xn[i][r] = *(const float*)(pbs + off[i][r] + 2048);
        }

        // epilogue: tanh, global store, scatter h into next A-buf
        const unsigned sbase = WLDS_B + (unsigned)(((t + 1) & 1) * 8192);
#pragma unroll
        for (int i = 0; i < 4; ++i) {
#pragma unroll
            for (int r = 0; r < 4; ++r) {
                float a = (lq < 2) ? acc[i][r] : acc[4 + i][r];
                float v = tanh_fast(a + xq[i][r] + bq[i]);
                *(float*)(pbs + off[i][r]) = v;
                *(_Float16*)(lds + sbase + (unsigned)sad[i] + (unsigned)(r * 16)) =
                    (_Float16)v;
                xq[i][r] = xn[i][r];
            }
        }
        pbs += 2048;
        __syncthreads();
    }
}

// ---------------------------------------------------------------------------
extern "C" void kernel_launch(void* const* d_in, const int* in_sizes, int n_in,
                              void* d_out, int out_size, void* d_ws, size_t ws_size,
                              hipStream_t stream) {
    const float* x   = (const float*)d_in[0];
    const float* wih = (const float*)d_in[1];
    const float* whh = (const float*)d_in[2];
    const float* bih = (const float*)d_in[3];
    const float* bhh = (const float*)d_in[4];
    float* out = (float*)d_out;

    dim3 g1(HH / P1_TN, (BB * SS) / P1_TM);
    xp_gemm<<<g1, 256, 0, stream>>>(x, wih, bih, out);

    static_assert(LDS_TOT <= 163840, "LDS over 160 KiB");
    hipFuncSetAttribute((const void*)rnn_scan3,
                        hipFuncAttributeMaxDynamicSharedMemorySize, LDS_TOT);
    rnn_scan3<<<dim3(1), dim3(256), LDS_TOT, stream>>>(whh, bhh, out);
}

// Round 4
// 11133.323 us; speedup vs baseline: 2.1701x; 1.3895x over previous
//
#include <hip/hip_runtime.h>
#include <hip/hip_fp16.h>

#define BB 8
#define SS 4096
#define II 512
#define HH 512

typedef _Float16 f16x8 __attribute__((ext_vector_type(8)));
typedef float f32x4 __attribute__((ext_vector_type(4)));

__device__ __forceinline__ float tanh_fast(float x) {
    // tanh(x) = 1 - 2/(exp2(2*log2e*x)+1); saturates correctly at +-inf
    float e = __builtin_amdgcn_exp2f(2.885390081777927f * x);
    return 1.0f - 2.0f * __builtin_amdgcn_rcpf(e + 1.0f);
}

// ---------------------------------------------------------------------------
// Phase 1: xp[m][n] = x[m][:] @ W_ih[n][:] + b_ih[n] + b_hh[n]   (b_hh folded)
// ---------------------------------------------------------------------------
#define P1_TM 64
#define P1_TN 64
#define P1_TK 16
#define P1_LDP 68

__global__ __launch_bounds__(256) void xp_gemm(const float* __restrict__ x,
                                               const float* __restrict__ wih,
                                               const float* __restrict__ bih,
                                               const float* __restrict__ bhh,
                                               float* __restrict__ out) {
    __shared__ float As[P1_TK][P1_LDP];
    __shared__ float Bs[P1_TK][P1_LDP];
    const int tid = threadIdx.x;
    const int n0  = blockIdx.x * P1_TN;
    const int m0  = blockIdx.y * P1_TM;
    const int row = tid >> 2;
    const int f4  = tid & 3;
    const int ty  = tid >> 4;
    const int tx  = tid & 15;

    float acc[4][4];
#pragma unroll
    for (int r = 0; r < 4; ++r)
#pragma unroll
        for (int c = 0; c < 4; ++c) acc[r][c] = 0.0f;

    const float* xa = x   + (size_t)(m0 + row) * II + f4 * 4;
    const float* wb = wih + (size_t)(n0 + row) * II + f4 * 4;

    for (int kb = 0; kb < II; kb += P1_TK) {
        float4 av = *(const float4*)(xa + kb);
        float4 bv = *(const float4*)(wb + kb);
        __syncthreads();
        As[f4 * 4 + 0][row] = av.x; As[f4 * 4 + 1][row] = av.y;
        As[f4 * 4 + 2][row] = av.z; As[f4 * 4 + 3][row] = av.w;
        Bs[f4 * 4 + 0][row] = bv.x; Bs[f4 * 4 + 1][row] = bv.y;
        Bs[f4 * 4 + 2][row] = bv.z; Bs[f4 * 4 + 3][row] = bv.w;
        __syncthreads();
#pragma unroll
        for (int kk = 0; kk < P1_TK; ++kk) {
            const float* a4 = &As[kk][ty * 4];
            const float* b4 = &Bs[kk][tx * 4];
#pragma unroll
            for (int r = 0; r < 4; ++r)
#pragma unroll
                for (int c = 0; c < 4; ++c)
                    acc[r][c] = fmaf(a4[r], b4[c], acc[r][c]);
        }
    }

    const float4 b1 = *(const float4*)&bih[n0 + tx * 4];
    const float4 b2 = *(const float4*)&bhh[n0 + tx * 4];
#pragma unroll
    for (int r = 0; r < 4; ++r) {
        float4 v;
        v.x = acc[r][0] + b1.x + b2.x;
        v.y = acc[r][1] + b1.y + b2.y;
        v.z = acc[r][2] + b1.z + b2.z;
        v.w = acc[r][3] + b1.w + b2.w;
        *(float4*)(out + (size_t)(m0 + ty * 4 + r) * HH + n0 + tx * 4) = v;
    }
}

// ---------------------------------------------------------------------------
// Phase 2: 1 CU, 8 waves (512 threads). Wave w owns n in [64w, 64w+64) =
// 4 tiles; tiles 0..2 -> W B-frags in regs (192 VGPR), tile 3 -> LDS stream
// (lane-private layout). All 8 batches in M of mfma_f32_16x16x32_f16; A rows
// 8..15 alias rows 0..7 (LDS broadcast) so all lanes hold valid outputs.
// A-frags in an 8KB double buffer (dedup'd, kb-parity XOR swizzle on m field).
// 1 barrier/step. b_hh pre-folded into xp by phase 1.
// ---------------------------------------------------------------------------
#define WLDS_B   (8 * 16 * 1024)       // 131072: 8 waves x 16KB streamed W tile
#define ABUF_OFF WLDS_B
#define LDS_TOT4 (WLDS_B + 2 * 8192)   // 147456 <= 163840

__device__ __forceinline__ f16x8 ldw(const float* __restrict__ whh, int n,
                                     int kb, int lq) {
    const float* p = whh + (size_t)n * HH + kb * 32 + lq * 8;
    float4 a = *(const float4*)p;
    float4 b = *(const float4*)(p + 4);
    f16x8 f;
    f[0] = (_Float16)a.x; f[1] = (_Float16)a.y;
    f[2] = (_Float16)a.z; f[3] = (_Float16)a.w;
    f[4] = (_Float16)b.x; f[5] = (_Float16)b.y;
    f[6] = (_Float16)b.z; f[7] = (_Float16)b.w;
    return f;
}

__global__ __launch_bounds__(512, 2) void rnn_scan4(const float* __restrict__ whh,
                                                    float* __restrict__ io) {
    extern __shared__ char lds[];
    const int tid = threadIdx.x;
    const int w   = tid >> 6;        // wave 0..7
    const int l   = tid & 63;
    const int l15 = l & 15;
    const int lq  = l >> 4;          // 0..3
    const int m8  = l15 & 7;
    const int mb  = (lq & 1) * 4;    // batch-row base this lane outputs

    // ---- W fragments: reg tiles gi=0..2, LDS tile gi=3 (lane-private)
    f16x8 wf0[16], wf1[16], wf2[16];
#pragma unroll
    for (int kb = 0; kb < 16; ++kb) {
        wf0[kb] = ldw(whh, w * 64 + 0 * 16 + l15, kb, lq);
        wf1[kb] = ldw(whh, w * 64 + 1 * 16 + l15, kb, lq);
        wf2[kb] = ldw(whh, w * 64 + 2 * 16 + l15, kb, lq);
        *(f16x8*)(lds + w * 16384 + kb * 1024 + l * 16) =
            ldw(whh, w * 64 + 3 * 16 + l15, kb, lq);
    }
    const char* wp = lds + w * 16384 + l * 16;

    // ---- per-lane output columns (s=0,1): gi = (lq>>1)*2 + s
    int xoff[2][4];   // global byte offsets: (mb+r)*SS*HH*4 + n_s*4
    int dsoff[2];     // A-buf scatter base (within one 8KB buffer)
#pragma unroll
    for (int s = 0; s < 2; ++s) {
        const int gi = (lq >> 1) * 2 + s;
        const int n  = w * 64 + gi * 16 + l15;
#pragma unroll
        for (int r = 0; r < 4; ++r)
            xoff[s][r] = (mb + r) * (SS * HH * 4) + n * 4;
        const int kb = n >> 5, ku = (n >> 3) & 3, ko = n & 7;
        dsoff[s] = kb * 512 + ku * 128 + ((mb ^ ((kb & 1) << 2)) * 16) + ko * 2;
    }

    __syncthreads();

#pragma unroll 1
    for (int t = 0; t < SS; ++t) {
        const char* pb = (const char*)io + (size_t)t * (HH * 4);

        // issue xp loads early (consumed in epilogue)
        float xv[2][4];
#pragma unroll
        for (int s = 0; s < 2; ++s)
#pragma unroll
            for (int r = 0; r < 4; ++r)
                xv[s][r] = *(const float*)(pb + xoff[s][r]);

        f32x4 acc0 = {0.f, 0.f, 0.f, 0.f}, acc1 = acc0, acc2 = acc0, acc3 = acc0;

        if (t > 0) {
            const unsigned rb = ABUF_OFF + (unsigned)(((t & 1) ^ 1) * 8192);
            const char* aE = lds + rb + lq * 128 + m8 * 16;
            const char* aO = lds + rb + lq * 128 + ((m8 ^ 4) * 16);
#pragma unroll
            for (int c = 0; c < 8; ++c) {   // 2-kb chunks, reg-pressure capped
                __builtin_amdgcn_sched_barrier(0);
#pragma unroll
                for (int k2 = 0; k2 < 2; ++k2) {
                    const int kb = c * 2 + k2;
                    f16x8 af = *(const f16x8*)(((kb & 1) ? aO : aE) + kb * 512);
                    f16x8 wl = *(const f16x8*)(wp + kb * 1024);
                    acc0 = __builtin_amdgcn_mfma_f32_16x16x32_f16(af, wf0[kb], acc0, 0, 0, 0);
                    acc1 = __builtin_amdgcn_mfma_f32_16x16x32_f16(af, wf1[kb], acc1, 0, 0, 0);
                    acc2 = __builtin_amdgcn_mfma_f32_16x16x32_f16(af, wf2[kb], acc2, 0, 0, 0);
                    acc3 = __builtin_amdgcn_mfma_f32_16x16x32_f16(af, wl,      acc3, 0, 0, 0);
                }
            }
            __builtin_amdgcn_sched_barrier(0);
        }

        // epilogue: tanh, global store (overwrite xp[t] with h[t]), A-scatter
        char* wB = lds + ABUF_OFF + (t & 1) * 8192;
#pragma unroll
        for (int s = 0; s < 2; ++s) {
#pragma unroll
            for (int r = 0; r < 4; ++r) {
                const float aa = (lq < 2)
                    ? (s == 0 ? acc0[r] : acc1[r])
                    : (s == 0 ? acc2[r] : acc3[r]);
                const float v = tanh_fast(aa + xv[s][r]);
                *(float*)(pb + xoff[s][r]) = v;
                *(_Float16*)(wB + dsoff[s] + r * 16) = (_Float16)v;
            }
        }
        __syncthreads();
    }
}

// ---------------------------------------------------------------------------
extern "C" void kernel_launch(void* const* d_in, const int* in_sizes, int n_in,
                              void* d_out, int out_size, void* d_ws, size_t ws_size,
                              hipStream_t stream) {
    const float* x   = (const float*)d_in[0];
    const float* wih = (const float*)d_in[1];
    const float* whh = (const float*)d_in[2];
    const float* bih = (const float*)d_in[3];
    const float* bhh = (const float*)d_in[4];
    float* out = (float*)d_out;

    dim3 g1(HH / P1_TN, (BB * SS) / P1_TM);
    xp_gemm<<<g1, 256, 0, stream>>>(x, wih, bih, bhh, out);

    static_assert(LDS_TOT4 <= 163840, "LDS over 160 KiB");
    hipFuncSetAttribute((const void*)rnn_scan4,
                        hipFuncAttributeMaxDynamicSharedMemorySize, LDS_TOT4);
    rnn_scan4<<<dim3(1), dim3(512), LDS_TOT4, stream>>>(whh, out);
}